// Round 15
// baseline (66.264 us; speedup 1.0000x reference)
//
#include <hip/hip_runtime.h>
#include <hip/hip_bf16.h>

#define D_MODEL 1024
#define STATE_N 256
#define BATCH 4
#define SEQ_LEN 4096
#define M_TOTAL (BATCH * SEQ_LEN)   // 16384
#define NCHUNK 128
#define CHUNK (SEQ_LEN / NCHUNK)    // 32

typedef __attribute__((ext_vector_type(8))) short bf16x8;
typedef __attribute__((ext_vector_type(4))) short s16x4;
typedef __attribute__((ext_vector_type(2))) short s16x2;
typedef __attribute__((ext_vector_type(4))) float f32x4;

static __device__ inline short f2bf(float f) {
    union { float f; unsigned u; } v; v.f = f;
    unsigned r = v.u + 0x7FFFu + ((v.u >> 16) & 1u);
    return (short)(r >> 16);
}
static __device__ inline short f2bf_hw(float f) {
    __hip_bfloat16 h = __float2bfloat16(f);
    return *reinterpret_cast<const short*>(&h);
}
static __device__ inline float bf2f(short s) {
    union { unsigned u; float f; } v;
    v.u = ((unsigned)(unsigned short)s) << 16;
    return v.f;
}
static __device__ inline float sigmoidf(float x) { return 1.0f / (1.0f + expf(-x)); }

#define GLOAD_LDS16(gp, lp)                                                     \
    __builtin_amdgcn_global_load_lds(                                           \
        (const __attribute__((address_space(1))) void*)(gp),                    \
        (__attribute__((address_space(3))) void*)(lp), 16, 0, 0)

#define WAITVM0   asm volatile("s_waitcnt vmcnt(0)" ::: "memory")
#define WAITVM4   asm volatile("s_waitcnt vmcnt(4)" ::: "memory")
#define WAITLGKM0 asm volatile("s_waitcnt lgkmcnt(0)" ::: "memory")
#define BARRIER() do { __builtin_amdgcn_s_barrier(); asm volatile("" ::: "memory"); } while (0)

// ---------------- prep: Bw,Cw fp32->bf16 tiled + lambda-power table ----------------
// Bwt: [cb 2][kt 32][kc 4][col 128][8]   (gemm1 B-tile order, BK=32)
// Cwt: [cbC 16][t 4][ksq 8][col 64][8]   (gemm2 B frag order)
// W:   [i 32][n 256] = lam[n]^(31-i)
__global__ void prep(const float* __restrict__ Bw, const float* __restrict__ Cw,
                     const float* __restrict__ ll,
                     short* __restrict__ Bwt, short* __restrict__ Cwt,
                     float* __restrict__ W) {
    const int bx = blockIdx.x, tid = threadIdx.x;
    if (bx >= 256) {   // W table: 32 blocks
        const int i = bx - 256, n = tid;
        W[i * 256 + n] = powf(sigmoidf(ll[n]), (float)(31 - i));
        return;
    }
    const int g = bx * 256 + tid;   // 65536 total
    const float* s; short* d;
    if (g < 32768) {
        const int col = g & 127, kc = (g >> 7) & 3, kt = (g >> 9) & 31, cb = g >> 14;
        s = Bw + (size_t)(cb * 128 + col) * D_MODEL + kt * 32 + kc * 8;
        d = Bwt + (size_t)g * 8;
    } else {
        const int h = g - 32768;
        const int col = h & 63, ksq = (h >> 6) & 7, tt = (h >> 9) & 3, cb = h >> 11;
        s = Cw + (size_t)(cb * 64 + col) * STATE_N + tt * 64 + ksq * 8;
        d = Cwt + (size_t)h * 8;
    }
    const f32x4 v0 = *(const f32x4*)s;
    const f32x4 v1 = *(const f32x4*)(s + 4);
    bf16x8 r;
    #pragma unroll
    for (int q = 0; q < 4; ++q) { r[q] = f2bf(v0[q]); r[4 + q] = f2bf(v1[q]); }
    *(bf16x8*)d = r;
}

// ---------------- GEMM1: Bu[m][n] = u[m][:].Bw[n][:], fused chunk-end reduce ----------------
// BM=64, BN=128 (cb half), BK=32, 32 K-tiles. A staged as FP32 via gload_lds
// (16B-granule XOR swizzle, cvt to bf16 at frag read, hw cvt); B bf16 gload_lds
// from pre-tiled Bwt (linear). 3-buffer, stage-ahead-2, WAITVM(4)/iter, one
// barrier/iter. 48KB LDS -> 3 blocks/CU.
__global__ __launch_bounds__(256, 3) void gemm1(const float* __restrict__ u,
                                                const short* __restrict__ Bwt,
                                                const float* __restrict__ W,
                                                short* __restrict__ Bu,
                                                float* __restrict__ ends) {
    __shared__ float As[3][64 * 32];       // 8KB/buf: [row 64][granule 8 ^row&7][4 fp32]
    __shared__ short Bs[3][4 * 128 * 8];   // 8KB/buf: [kc 4][col 128][8]
    const int tid = threadIdx.x;
    const int lane = tid & 63, wave = tid >> 6;
    const int lr = lane & 15, kq = lane >> 4;
    const int wr = wave >> 1, wc = wave & 1;
    const int wg = ((blockIdx.x & 7) << 6) + (blockIdx.x >> 3);  // 512 = 8*64 bijective
    const int cb = wg & 1, strip = wg >> 1;
    const int m0 = strip * 64, n0 = cb * 128;

    const int r0 = tid >> 3, gx = tid & 7;
    const int sw0 = r0 & 7;
    const float* asrc0 = u + (size_t)(m0 + r0) * D_MODEL + ((gx ^ sw0) << 2);
    const float* asrc1 = u + (size_t)(m0 + 32 + r0) * D_MODEL + ((gx ^ sw0) << 2);
    const short* bsrc = Bwt + (size_t)cb * 32 * 4096;

    #define STAGE1(BUF, KT)                                                      \
        do { GLOAD_LDS16(asrc0 + (KT) * 32, (char*)&As[BUF][0] + (wave * 64) * 16);        \
             GLOAD_LDS16(asrc1 + (KT) * 32, (char*)&As[BUF][0] + (256 + wave * 64) * 16);  \
             const short* bs_ = bsrc + (size_t)(KT) * 4096;                      \
             GLOAD_LDS16(bs_ + (size_t)tid * 8,       (char*)&Bs[BUF][0] + (wave * 64) * 16);       \
             GLOAD_LDS16(bs_ + (size_t)(256 + tid) * 8, (char*)&Bs[BUF][0] + (256 + wave * 64) * 16); \
        } while (0)

    f32x4 acc[2][4] = {};

    STAGE1(0, 0);
    STAGE1(1, 1);

    #pragma unroll
    for (int t = 0; t < 32; ++t) {
        if (t < 31) { WAITVM4; } else { WAITVM0; }
        BARRIER();
        if (t + 2 <= 31) STAGE1((t + 2) % 3, t + 2);

        bf16x8 af[2];
        bf16x8 bfr[4];
        #pragma unroll
        for (int i = 0; i < 2; ++i) {
            const int row = wr * 32 + i * 16 + lr;
            const int sw = row & 7;
            const f32x4 a0 = *(const f32x4*)&As[t % 3][row * 32 + ((((kq << 1)    ) ^ sw) << 2)];
            const f32x4 a1 = *(const f32x4*)&As[t % 3][row * 32 + ((((kq << 1) | 1) ^ sw) << 2)];
            #pragma unroll
            for (int e = 0; e < 4; ++e) { af[i][e] = f2bf_hw(a0[e]); af[i][4 + e] = f2bf_hw(a1[e]); }
        }
        #pragma unroll
        for (int j = 0; j < 4; ++j)
            bfr[j] = *(const bf16x8*)&Bs[t % 3][(kq * 128 + wc * 64 + j * 16 + lr) * 8];
        #pragma unroll
        for (int i = 0; i < 2; ++i)
            #pragma unroll
            for (int j = 0; j < 4; ++j)
                acc[i][j] = __builtin_amdgcn_mfma_f32_16x16x32_bf16(bfr[j], af[i], acc[i][j], 0, 0, 0);
    }
    #undef STAGE1

    // Bu stores (swapped layout: m = lr-row, 4 consecutive n per f32x4)
    #pragma unroll
    for (int i = 0; i < 2; ++i) {
        const int m = m0 + wr * 32 + i * 16 + lr;
        #pragma unroll
        for (int j = 0; j < 4; ++j) {
            const int n = n0 + wc * 64 + j * 16 + kq * 4;
            s16x4 st;
            #pragma unroll
            for (int r = 0; r < 4; ++r) st[r] = f2bf(acc[i][j][r]);
            *(s16x4*)(Bu + (size_t)m * STATE_N + n) = st;
        }
    }

    // fused chunk-end reduce: ends[strip*2+wr][n] = sum_row lam^(31-row)*Bu
    float part[4][4];
    #pragma unroll
    for (int j = 0; j < 4; ++j) {
        const int nb = n0 + wc * 64 + j * 16 + kq * 4;
        const f32x4 w0 = *(const f32x4*)(W + (size_t)lr * 256 + nb);
        const f32x4 w1 = *(const f32x4*)(W + (size_t)(16 + lr) * 256 + nb);
        #pragma unroll
        for (int r = 0; r < 4; ++r)
            part[j][r] = w0[r] * acc[0][j][r] + w1[r] * acc[1][j][r];
    }
    #pragma unroll
    for (int m = 1; m <= 8; m <<= 1)
        #pragma unroll
        for (int j = 0; j < 4; ++j)
            #pragma unroll
            for (int r = 0; r < 4; ++r)
                part[j][r] += __shfl_xor(part[j][r], m, 64);
    if (lr == 0) {
        const int cg = strip * 2 + wr;
        #pragma unroll
        for (int j = 0; j < 4; ++j) {
            f32x4 e;
            #pragma unroll
            for (int r = 0; r < 4; ++r) e[r] = part[j][r];
            *(f32x4*)(ends + (size_t)cg * STATE_N + n0 + wc * 64 + j * 16 + kq * 4) = e;
        }
    }
}

// ---------------- GEMM2 (fused scan): h = scan(Bu), y = h.Cw^T + D*u ----------------
// Block = 32 rows (ONE scan chunk) x 256 cols, grid 2048, 16KB LDS, 3 blocks/CU.
// Stage the [32][256] Bu tile via gload_lds (granule-XOR swizzle), scan 1 col
// per thread, then barrier-free MFMA loop (K=256 in one tile), B fragments
// direct from L2-resident Cwt (regs, 1 tile ahead). Vector u/y epilogue.
__global__ __launch_bounds__(256, 3) void gemm2(const short* __restrict__ Bu,
                                                const short* __restrict__ Cwt,
                                                const float* __restrict__ ll,
                                                const float* __restrict__ carries,
                                                const float* __restrict__ u,
                                                const float* __restrict__ Dv,
                                                float* __restrict__ y) {
    __shared__ short Ash[32 * 256];        // 16KB: [row 32][granule 32 ^(row&7)][8]
    const int tid = threadIdx.x;
    const int lane = tid & 63, wave = tid >> 6;   // wave = 64-col group
    const int lr = lane & 15, kq = lane >> 4;
    const int wg = ((blockIdx.x & 7) << 8) + (blockIdx.x >> 3);  // 2048 = 8*256 bijective
    const int cb = wg & 3, strip = wg >> 2;       // strip = global chunk id (0..511)
    const int m0 = strip * 32;

    // scalar loads for the scan (drained by the vmcnt(0) below)
    const float lam = sigmoidf(ll[tid]);
    float h = carries[(size_t)strip * STATE_N + tid];

    // A staging: slot = q*256+tid; row = slot>>5, p = slot&31; src granule = p^(row&7)
    const int arow = tid >> 5, ap = tid & 31;     // per-q: row = arow + q*8
    const short* bg = Cwt + (size_t)(cb * 4 + wave) * 16384;   // [t 4][ksq 8][col 64][8]

    #pragma unroll
    for (int q = 0; q < 4; ++q) {
        const int row = q * 8 + arow;
        const short* src = Bu + (size_t)(m0 + row) * STATE_N + ((ap ^ (row & 7)) << 3);
        GLOAD_LDS16(src, (char*)&Ash[0] + (q * 256 + wave * 64) * 16);
    }
    WAITVM0;
    BARRIER();

    bf16x8 bfr[2][2][4];                   // [buf][ks][j]
    #define LOADB2(BUF, T)                                                       \
        do { _Pragma("unroll")                                                   \
             for (int ks = 0; ks < 2; ++ks)                                      \
                 _Pragma("unroll")                                               \
                 for (int j = 0; j < 4; ++j)                                     \
                     bfr[BUF][ks][j] = *(const bf16x8*)(bg + (size_t)(T) * 4096  \
                         + (((ks << 2) | kq) * 64 + j * 16 + lr) * 8); } while (0)

    LOADB2(0, 0);                          // flies under the scan

    // ---- in-LDS seeded scan: thread owns column tid over the 32 rows ----
    {
        const int g = tid >> 3, s = tid & 7;
        #pragma unroll
        for (int i = 0; i < 32; ++i) {
            const int a = (i * 32 + (g ^ (i & 7))) * 8 + s;
            h = fmaf(lam, h, bf2f(Ash[a]));
            Ash[a] = f2bf_hw(h);
        }
    }
    WAITLGKM0;
    BARRIER();

    // ---- barrier-free MFMA loop (Ash read-only from here): K=256, 4 sub-tiles ----
    f32x4 acc[2][4] = {};
    #pragma unroll
    for (int t = 0; t < 4; ++t) {
        bf16x8 af[2][2];                   // [ks][i]
        #pragma unroll
        for (int ks = 0; ks < 2; ++ks)
            #pragma unroll
            for (int i = 0; i < 2; ++i) {
                const int row = i * 16 + lr;
                const int gk = t * 8 + ks * 4 + kq;
                af[ks][i] = *(const bf16x8*)&Ash[(row * 32 + (gk ^ (row & 7))) * 8];
            }
        if (t < 3) LOADB2((t + 1) & 1, t + 1);
        #pragma unroll
        for (int ks = 0; ks < 2; ++ks)
            #pragma unroll
            for (int i = 0; i < 2; ++i)
                #pragma unroll
                for (int j = 0; j < 4; ++j)
                    acc[i][j] = __builtin_amdgcn_mfma_f32_16x16x32_bf16(bfr[t & 1][ks][j], af[ks][i], acc[i][j], 0, 0, 0);
    }
    #undef LOADB2

    // epilogue: m = i*16+lr row, n = cb*256 + wave*64 + j*16 + kq*4 (4 consecutive)
    #pragma unroll
    for (int i = 0; i < 2; ++i) {
        const int m = m0 + i * 16 + lr;
        #pragma unroll
        for (int j = 0; j < 4; ++j) {
            const int n = cb * 256 + wave * 64 + j * 16 + kq * 4;
            const size_t o = (size_t)m * D_MODEL + n;
            const f32x4 uv = *(const f32x4*)(u + o);
            const f32x4 dv = *(const f32x4*)(Dv + n);
            f32x4 rv;
            #pragma unroll
            for (int q = 0; q < 4; ++q) rv[q] = fmaf(dv[q], uv[q], acc[i][j][q]);
            *(f32x4*)(y + o) = rv;
        }
    }
}

// ---------------- Scan pass 2: carry scan across chunks ----------------
__global__ void scan_carry(const float* __restrict__ ends,
                           const float* __restrict__ log_lambda,
                           float* __restrict__ carries) {
    const int n = threadIdx.x;
    const int b = blockIdx.x;
    const float lam = sigmoidf(log_lambda[n]);
    const float lamC = powf(lam, (float)CHUNK);
    float carry = 0.0f;
    #pragma unroll 16
    for (int c = 0; c < NCHUNK; ++c) {
        const size_t o = ((size_t)(b * NCHUNK + c)) * STATE_N + n;
        carries[o] = carry;
        carry = fmaf(lamC, carry, ends[o]);
    }
}

extern "C" void kernel_launch(void* const* d_in, const int* in_sizes, int n_in,
                              void* d_out, int out_size, void* d_ws, size_t ws_size,
                              hipStream_t stream) {
    const float* u  = (const float*)d_in[0];
    const float* ll = (const float*)d_in[1];
    const float* Bw = (const float*)d_in[2];
    const float* Cw = (const float*)d_in[3];
    const float* Dv = (const float*)d_in[4];
    float* y = (float*)d_out;

    char* ws = (char*)d_ws;
    size_t off = 0;
    short* Bwt = (short*)(ws + off); off += (size_t)STATE_N * D_MODEL * 2;      // 512 KB
    short* Cwt = (short*)(ws + off); off += (size_t)D_MODEL * STATE_N * 2;      // 512 KB
    float* W   = (float*)(ws + off); off += (size_t)32 * STATE_N * 4;           // 32 KB
    short* Bu  = (short*)(ws + off); off += (size_t)M_TOTAL * STATE_N * 2;      // 8 MB
    float* ends = (float*)(ws + off); off += (size_t)BATCH * NCHUNK * STATE_N * 4;
    float* carries = (float*)(ws + off);

    prep<<<288, 256, 0, stream>>>(Bw, Cw, ll, Bwt, Cwt, W);
    gemm1<<<512, 256, 0, stream>>>(u, Bwt, W, Bu, ends);
    scan_carry<<<BATCH, STATE_N, 0, stream>>>(ends, ll, carries);
    gemm2<<<2048, 256, 0, stream>>>(Bu, Cwt, ll, carries, u, Dv, y);
}

// Round 16
// 64.391 us; speedup vs baseline: 1.0291x; 1.0291x over previous
//
#include <hip/hip_runtime.h>
#include <hip/hip_bf16.h>

#define D_MODEL 1024
#define STATE_N 256
#define BATCH 4
#define SEQ_LEN 4096
#define M_TOTAL (BATCH * SEQ_LEN)   // 16384
#define NCHUNK 128
#define CHUNK (SEQ_LEN / NCHUNK)    // 32

typedef __attribute__((ext_vector_type(8))) short bf16x8;
typedef __attribute__((ext_vector_type(4))) short s16x4;
typedef __attribute__((ext_vector_type(2))) short s16x2;
typedef __attribute__((ext_vector_type(4))) float f32x4;

static __device__ inline short f2bf(float f) {
    union { float f; unsigned u; } v; v.f = f;
    unsigned r = v.u + 0x7FFFu + ((v.u >> 16) & 1u);
    return (short)(r >> 16);
}
static __device__ inline short f2bf_hw(float f) {
    __hip_bfloat16 h = __float2bfloat16(f);
    return *reinterpret_cast<const short*>(&h);
}
static __device__ inline float bf2f(short s) {
    union { unsigned u; float f; } v;
    v.u = ((unsigned)(unsigned short)s) << 16;
    return v.f;
}
static __device__ inline float sigmoidf(float x) { return 1.0f / (1.0f + expf(-x)); }

#define GLOAD_LDS16(gp, lp)                                                     \
    __builtin_amdgcn_global_load_lds(                                           \
        (const __attribute__((address_space(1))) void*)(gp),                    \
        (__attribute__((address_space(3))) void*)(lp), 16, 0, 0)

#define WAITVM0   asm volatile("s_waitcnt vmcnt(0)" ::: "memory")
#define WAITVM4   asm volatile("s_waitcnt vmcnt(4)" ::: "memory")
#define WAITVMN(N) asm volatile("s_waitcnt vmcnt(" #N ")" ::: "memory")
#define WAITLGKM0 asm volatile("s_waitcnt lgkmcnt(0)" ::: "memory")
#define BARRIER() do { __builtin_amdgcn_s_barrier(); asm volatile("" ::: "memory"); } while (0)

// ---------------- prep: Bw,Cw fp32->bf16 tiled + lambda-power table ----------------
// Bwt: [cb 2][kt 32][kc 4][col 128][8]   (gemm1 B-tile order, BK=32)
// Cwt: [cbC 16][t 4][ksq 8][col 64][8]   (gemm2 B frag order)
// W:   [i 32][n 256] = lam[n]^(31-i)
__global__ void prep(const float* __restrict__ Bw, const float* __restrict__ Cw,
                     const float* __restrict__ ll,
                     short* __restrict__ Bwt, short* __restrict__ Cwt,
                     float* __restrict__ W) {
    const int bx = blockIdx.x, tid = threadIdx.x;
    if (bx >= 256) {   // W table: 32 blocks
        const int i = bx - 256, n = tid;
        W[i * 256 + n] = powf(sigmoidf(ll[n]), (float)(31 - i));
        return;
    }
    const int g = bx * 256 + tid;   // 65536 total
    const float* s; short* d;
    if (g < 32768) {
        const int col = g & 127, kc = (g >> 7) & 3, kt = (g >> 9) & 31, cb = g >> 14;
        s = Bw + (size_t)(cb * 128 + col) * D_MODEL + kt * 32 + kc * 8;
        d = Bwt + (size_t)g * 8;
    } else {
        const int h = g - 32768;
        const int col = h & 63, ksq = (h >> 6) & 7, tt = (h >> 9) & 3, cb = h >> 11;
        s = Cw + (size_t)(cb * 64 + col) * STATE_N + tt * 64 + ksq * 8;
        d = Cwt + (size_t)h * 8;
    }
    const f32x4 v0 = *(const f32x4*)s;
    const f32x4 v1 = *(const f32x4*)(s + 4);
    bf16x8 r;
    #pragma unroll
    for (int q = 0; q < 4; ++q) { r[q] = f2bf(v0[q]); r[4 + q] = f2bf(v1[q]); }
    *(bf16x8*)d = r;
}

// ---------------- GEMM1: Bu[m][n] = u[m][:].Bw[n][:], fused chunk-end reduce ----------------
// BM=64, BN=128 (cb half), BK=32, 32 K-tiles. A staged as FP32 via gload_lds
// (16B-granule XOR swizzle, cvt to bf16 at frag read, hw cvt); B bf16 gload_lds
// from pre-tiled Bwt (linear). 3-buffer, stage-ahead-2, WAITVM(4)/iter, one
// barrier/iter. 48KB LDS -> 3 blocks/CU.
__global__ __launch_bounds__(256, 3) void gemm1(const float* __restrict__ u,
                                                const short* __restrict__ Bwt,
                                                const float* __restrict__ W,
                                                short* __restrict__ Bu,
                                                float* __restrict__ ends) {
    __shared__ float As[3][64 * 32];       // 8KB/buf: [row 64][granule 8 ^row&7][4 fp32]
    __shared__ short Bs[3][4 * 128 * 8];   // 8KB/buf: [kc 4][col 128][8]
    const int tid = threadIdx.x;
    const int lane = tid & 63, wave = tid >> 6;
    const int lr = lane & 15, kq = lane >> 4;
    const int wr = wave >> 1, wc = wave & 1;
    const int wg = ((blockIdx.x & 7) << 6) + (blockIdx.x >> 3);  // 512 = 8*64 bijective
    const int cb = wg & 1, strip = wg >> 1;
    const int m0 = strip * 64, n0 = cb * 128;

    const int r0 = tid >> 3, gx = tid & 7;
    const int sw0 = r0 & 7;
    const float* asrc0 = u + (size_t)(m0 + r0) * D_MODEL + ((gx ^ sw0) << 2);
    const float* asrc1 = u + (size_t)(m0 + 32 + r0) * D_MODEL + ((gx ^ sw0) << 2);
    const short* bsrc = Bwt + (size_t)cb * 32 * 4096;

    #define STAGE1(BUF, KT)                                                      \
        do { GLOAD_LDS16(asrc0 + (KT) * 32, (char*)&As[BUF][0] + (wave * 64) * 16);        \
             GLOAD_LDS16(asrc1 + (KT) * 32, (char*)&As[BUF][0] + (256 + wave * 64) * 16);  \
             const short* bs_ = bsrc + (size_t)(KT) * 4096;                      \
             GLOAD_LDS16(bs_ + (size_t)tid * 8,       (char*)&Bs[BUF][0] + (wave * 64) * 16);       \
             GLOAD_LDS16(bs_ + (size_t)(256 + tid) * 8, (char*)&Bs[BUF][0] + (256 + wave * 64) * 16); \
        } while (0)

    f32x4 acc[2][4] = {};

    STAGE1(0, 0);
    STAGE1(1, 1);

    #pragma unroll
    for (int t = 0; t < 32; ++t) {
        if (t < 31) { WAITVM4; } else { WAITVM0; }
        BARRIER();
        if (t + 2 <= 31) STAGE1((t + 2) % 3, t + 2);

        bf16x8 af[2];
        bf16x8 bfr[4];
        #pragma unroll
        for (int i = 0; i < 2; ++i) {
            const int row = wr * 32 + i * 16 + lr;
            const int sw = row & 7;
            const f32x4 a0 = *(const f32x4*)&As[t % 3][row * 32 + ((((kq << 1)    ) ^ sw) << 2)];
            const f32x4 a1 = *(const f32x4*)&As[t % 3][row * 32 + ((((kq << 1) | 1) ^ sw) << 2)];
            #pragma unroll
            for (int e = 0; e < 4; ++e) { af[i][e] = f2bf_hw(a0[e]); af[i][4 + e] = f2bf_hw(a1[e]); }
        }
        #pragma unroll
        for (int j = 0; j < 4; ++j)
            bfr[j] = *(const bf16x8*)&Bs[t % 3][(kq * 128 + wc * 64 + j * 16 + lr) * 8];
        #pragma unroll
        for (int i = 0; i < 2; ++i)
            #pragma unroll
            for (int j = 0; j < 4; ++j)
                acc[i][j] = __builtin_amdgcn_mfma_f32_16x16x32_bf16(bfr[j], af[i], acc[i][j], 0, 0, 0);
    }
    #undef STAGE1

    // Bu stores (swapped layout: m = lr-row, 4 consecutive n per f32x4)
    #pragma unroll
    for (int i = 0; i < 2; ++i) {
        const int m = m0 + wr * 32 + i * 16 + lr;
        #pragma unroll
        for (int j = 0; j < 4; ++j) {
            const int n = n0 + wc * 64 + j * 16 + kq * 4;
            s16x4 st;
            #pragma unroll
            for (int r = 0; r < 4; ++r) st[r] = f2bf(acc[i][j][r]);
            *(s16x4*)(Bu + (size_t)m * STATE_N + n) = st;
        }
    }

    // fused chunk-end reduce: ends[strip*2+wr][n] = sum_row lam^(31-row)*Bu
    float part[4][4];
    #pragma unroll
    for (int j = 0; j < 4; ++j) {
        const int nb = n0 + wc * 64 + j * 16 + kq * 4;
        const f32x4 w0 = *(const f32x4*)(W + (size_t)lr * 256 + nb);
        const f32x4 w1 = *(const f32x4*)(W + (size_t)(16 + lr) * 256 + nb);
        #pragma unroll
        for (int r = 0; r < 4; ++r)
            part[j][r] = w0[r] * acc[0][j][r] + w1[r] * acc[1][j][r];
    }
    #pragma unroll
    for (int m = 1; m <= 8; m <<= 1)
        #pragma unroll
        for (int j = 0; j < 4; ++j)
            #pragma unroll
            for (int r = 0; r < 4; ++r)
                part[j][r] += __shfl_xor(part[j][r], m, 64);
    if (lr == 0) {
        const int cg = strip * 2 + wr;
        #pragma unroll
        for (int j = 0; j < 4; ++j) {
            f32x4 e;
            #pragma unroll
            for (int r = 0; r < 4; ++r) e[r] = part[j][r];
            *(f32x4*)(ends + (size_t)cg * STATE_N + n0 + wc * 64 + j * 16 + kq * 4) = e;
        }
    }
}

// ---------------- GEMM2 (fused scan): h = scan(Bu), y = h.Cw^T + D*u ----------------
// Block = 32 rows (ONE scan chunk) x 256 cols, grid 2048, 16KB LDS, 3 blocks/CU.
// A-DMA issued FIRST, then B-tile-0 + u-epilogue prefetch fly under scan+MFMA
// (counted vmcnt(16): 22 vmem ops issued, in-order retire => A complete).
// Barrier-free MFMA loop; non-temporal y stores.
__global__ __launch_bounds__(256, 3) void gemm2(const short* __restrict__ Bu,
                                                const short* __restrict__ Cwt,
                                                const float* __restrict__ ll,
                                                const float* __restrict__ carries,
                                                const float* __restrict__ u,
                                                const float* __restrict__ Dv,
                                                float* __restrict__ y) {
    __shared__ short Ash[32 * 256];        // 16KB: [row 32][granule 32 ^(row&7)][8]
    const int tid = threadIdx.x;
    const int lane = tid & 63, wave = tid >> 6;   // wave = 64-col group
    const int lr = lane & 15, kq = lane >> 4;
    const int wg = ((blockIdx.x & 7) << 8) + (blockIdx.x >> 3);  // 2048 = 8*256 bijective
    const int cb = wg & 3, strip = wg >> 2;       // strip = global chunk id (0..511)
    const int m0 = strip * 32;

    const int arow = tid >> 5, ap = tid & 31;     // per-q: row = arow + q*8
    const short* bg = Cwt + (size_t)(cb * 4 + wave) * 16384;   // [t 4][ksq 8][col 64][8]

    // ---- A-DMA first: the 4 oldest vmem ops ----
    #pragma unroll
    for (int q = 0; q < 4; ++q) {
        const int row = q * 8 + arow;
        const short* src = Bu + (size_t)(m0 + row) * STATE_N + ((ap ^ (row & 7)) << 3);
        GLOAD_LDS16(src, (char*)&Ash[0] + (q * 256 + wave * 64) * 16);
    }

    bf16x8 bfr[2][2][4];                   // [buf][ks][j]
    #define LOADB2(BUF, T)                                                       \
        do { _Pragma("unroll")                                                   \
             for (int ks = 0; ks < 2; ++ks)                                      \
                 _Pragma("unroll")                                               \
                 for (int j = 0; j < 4; ++j)                                     \
                     bfr[BUF][ks][j] = *(const bf16x8*)(bg + (size_t)(T) * 4096  \
                         + (((ks << 2) | kq) * 64 + j * 16 + lr) * 8); } while (0)

    LOADB2(0, 0);                          // 8 loads, fly under the scan

    // ---- u epilogue prefetch (8 f32x4) — lands under scan + MFMA ----
    f32x4 uv[2][4];
    #pragma unroll
    for (int i = 0; i < 2; ++i)
        #pragma unroll
        for (int j = 0; j < 4; ++j) {
            const int m = m0 + i * 16 + lr;
            const int n = cb * 256 + wave * 64 + j * 16 + kq * 4;
            uv[i][j] = *(const f32x4*)(u + (size_t)m * D_MODEL + n);
        }

    // scan seeds (2 more vmem ops; total issued before wait = 22)
    const float lam = sigmoidf(ll[tid]);
    float h = carries[(size_t)strip * STATE_N + tid];

    WAITVMN(16);           // retired >= 22-16 = 6 oldest => all 4 A-DMA complete
    BARRIER();

    // ---- in-LDS seeded scan: thread owns column tid over the 32 rows ----
    {
        const int g = tid >> 3, s = tid & 7;
        #pragma unroll
        for (int i = 0; i < 32; ++i) {
            const int a = (i * 32 + (g ^ (i & 7))) * 8 + s;
            h = fmaf(lam, h, bf2f(Ash[a]));
            Ash[a] = f2bf_hw(h);
        }
    }
    WAITLGKM0;
    BARRIER();

    // ---- barrier-free MFMA loop (Ash read-only from here): K=256, 4 sub-tiles ----
    f32x4 acc[2][4] = {};
    #pragma unroll
    for (int t = 0; t < 4; ++t) {
        bf16x8 af[2][2];                   // [ks][i]
        #pragma unroll
        for (int ks = 0; ks < 2; ++ks)
            #pragma unroll
            for (int i = 0; i < 2; ++i) {
                const int row = i * 16 + lr;
                const int gk = t * 8 + ks * 4 + kq;
                af[ks][i] = *(const bf16x8*)&Ash[(row * 32 + (gk ^ (row & 7))) * 8];
            }
        if (t < 3) LOADB2((t + 1) & 1, t + 1);
        #pragma unroll
        for (int ks = 0; ks < 2; ++ks)
            #pragma unroll
            for (int i = 0; i < 2; ++i)
                #pragma unroll
                for (int j = 0; j < 4; ++j)
                    acc[i][j] = __builtin_amdgcn_mfma_f32_16x16x32_bf16(bfr[t & 1][ks][j], af[ks][i], acc[i][j], 0, 0, 0);
    }
    #undef LOADB2

    // epilogue: prefetched u, fresh Dv (4KB L2-warm), NON-TEMPORAL y stores
    #pragma unroll
    for (int i = 0; i < 2; ++i) {
        const int m = m0 + i * 16 + lr;
        #pragma unroll
        for (int j = 0; j < 4; ++j) {
            const int n = cb * 256 + wave * 64 + j * 16 + kq * 4;
            const size_t o = (size_t)m * D_MODEL + n;
            const f32x4 dv = *(const f32x4*)(Dv + n);
            f32x4 rv;
            #pragma unroll
            for (int q = 0; q < 4; ++q) rv[q] = fmaf(dv[q], uv[i][j][q], acc[i][j][q]);
            __builtin_nontemporal_store(rv, (f32x4*)(y + o));
        }
    }
}

// ---------------- Scan pass 2: carry scan across chunks ----------------
__global__ void scan_carry(const float* __restrict__ ends,
                           const float* __restrict__ log_lambda,
                           float* __restrict__ carries) {
    const int n = threadIdx.x;
    const int b = blockIdx.x;
    const float lam = sigmoidf(log_lambda[n]);
    const float lamC = powf(lam, (float)CHUNK);
    float carry = 0.0f;
    #pragma unroll 16
    for (int c = 0; c < NCHUNK; ++c) {
        const size_t o = ((size_t)(b * NCHUNK + c)) * STATE_N + n;
        carries[o] = carry;
        carry = fmaf(lamC, carry, ends[o]);
    }
}

extern "C" void kernel_launch(void* const* d_in, const int* in_sizes, int n_in,
                              void* d_out, int out_size, void* d_ws, size_t ws_size,
                              hipStream_t stream) {
    const float* u  = (const float*)d_in[0];
    const float* ll = (const float*)d_in[1];
    const float* Bw = (const float*)d_in[2];
    const float* Cw = (const float*)d_in[3];
    const float* Dv = (const float*)d_in[4];
    float* y = (float*)d_out;

    char* ws = (char*)d_ws;
    size_t off = 0;
    short* Bwt = (short*)(ws + off); off += (size_t)STATE_N * D_MODEL * 2;      // 512 KB
    short* Cwt = (short*)(ws + off); off += (size_t)D_MODEL * STATE_N * 2;      // 512 KB
    float* W   = (float*)(ws + off); off += (size_t)32 * STATE_N * 4;           // 32 KB
    short* Bu  = (short*)(ws + off); off += (size_t)M_TOTAL * STATE_N * 2;      // 8 MB
    float* ends = (float*)(ws + off); off += (size_t)BATCH * NCHUNK * STATE_N * 4;
    float* carries = (float*)(ws + off);

    prep<<<288, 256, 0, stream>>>(Bw, Cw, ll, Bwt, Cwt, W);
    gemm1<<<512, 256, 0, stream>>>(u, Bwt, W, Bu, ends);
    scan_carry<<<BATCH, STATE_N, 0, stream>>>(ends, ll, carries);
    gemm2<<<2048, 256, 0, stream>>>(Bu, Cwt, ll, carries, u, Dv, y);
}